// Round 8
// baseline (470.525 us; speedup 1.0000x reference)
//
#include <hip/hip_runtime.h>

typedef unsigned short u16;
typedef unsigned int u32;
typedef unsigned long long u64;
typedef __attribute__((ext_vector_type(8))) short bf16x8;
typedef __attribute__((ext_vector_type(4))) float f32x4;

__device__ __forceinline__ float b2f(u16 v) {
  union { u32 u; float f; } c; c.u = ((u32)v) << 16; return c.f;
}
__device__ __forceinline__ u16 f2b(float f) {
  union { float f; u32 u; } c; c.f = f;
  return (u16)((c.u + 0x7fffu + ((c.u >> 16) & 1u)) >> 16);
}

// async global->LDS, 16B per lane (global_load_lds_dwordx4).
__device__ __forceinline__ void g2l16(const u16* g, u16* l) {
  __builtin_amdgcn_global_load_lds(
      (const __attribute__((address_space(1))) u32*)g,
      (__attribute__((address_space(3))) u32*)l,
      16, 0, 0);
}

// tanh-form GELU: verified rounds 1-7 (absmax unchanged at 0.0625).
__device__ __forceinline__ float gelu_fast(float x) {
  float z2 = -1.5957691216057308f * x * (1.0f + 0.044715f * x * x);  // -2z
  z2 = fminf(fmaxf(z2, -30.f), 30.f);
  float t = __expf(z2);
  return x * __builtin_amdgcn_rcpf(1.0f + t);
}

// ---------------- LDS-tiled weight repacks (fp32 in -> bf16 out) -------------
__global__ __launch_bounds__(256)
void repack_qkv_tiled(const float* __restrict__ Wq, const float* __restrict__ Wk,
                      const float* __restrict__ Wv, u16* __restrict__ WT) {
  __shared__ u16 tile[64][65];
  const int sh = blockIdx.y, sel = sh >> 4, h = sh & 15;
  const float* W = (sel == 0) ? Wq : ((sel == 1) ? Wk : Wv);
  const int k0 = blockIdx.x * 64;
  {
    const int d = threadIdx.x & 63, r = threadIdx.x >> 6;
    #pragma unroll
    for (int i = 0; i < 16; ++i) {
      int k = r * 16 + i;
      tile[k][d] = f2b(W[(size_t)h * 65536 + (size_t)(k0 + k) * 64 + d]);
    }
  }
  __syncthreads();
  {
    const int k = threadIdx.x & 63, dd = threadIdx.x >> 6;
    #pragma unroll
    for (int i = 0; i < 16; ++i) {
      int d2 = dd * 16 + i;
      WT[((size_t)sel * 1024 + h * 64 + d2) * 1024 + k0 + k] = tile[k][d2];
    }
  }
}

__global__ __launch_bounds__(256)
void transpose_tiled(const float* __restrict__ W, u16* __restrict__ WT,
                     int N, int K) {
  __shared__ u16 tile[32][33];
  const int bx = blockIdx.x * 32;   // n
  const int by = blockIdx.y * 32;   // k
  const int tx = threadIdx.x & 31, ty = threadIdx.x >> 5;
  #pragma unroll
  for (int i = 0; i < 4; ++i) {
    int k = ty + i * 8;
    tile[k][tx] = f2b(W[(size_t)(by + k) * N + bx + tx]);
  }
  __syncthreads();
  #pragma unroll
  for (int i = 0; i < 4; ++i) {
    int n = ty + i * 8;
    WT[(size_t)(bx + n) * K + by + tx] = tile[tx][n];
  }
}

// ---------------- LayerNorm (C=1024, EPS=1e-3), bf16 out ----------------
__global__ __launch_bounds__(256)
void ln_f32_kernel(const float* __restrict__ X, const float* __restrict__ G,
                   const float* __restrict__ Bt, u16* __restrict__ O) {
  const int row = blockIdx.x;
  const int tid = threadIdx.x;
  const float* xr = X + (size_t)row * 1024;
  float4 xv = *(const float4*)(xr + tid * 4);
  float v0 = xv.x, v1 = xv.y, v2 = xv.z, v3 = xv.w;
  float s = v0 + v1 + v2 + v3;
  float q = v0 * v0 + v1 * v1 + v2 * v2 + v3 * v3;
  #pragma unroll
  for (int off = 32; off > 0; off >>= 1) {
    s += __shfl_down(s, off);
    q += __shfl_down(q, off);
  }
  __shared__ float red[8];
  int wave = tid >> 6, lane = tid & 63;
  if (lane == 0) { red[wave] = s; red[4 + wave] = q; }
  __syncthreads();
  s = red[0] + red[1] + red[2] + red[3];
  q = red[4] + red[5] + red[6] + red[7];
  float mean = s * (1.f / 1024.f);
  float var = q * (1.f / 1024.f) - mean * mean;
  float rstd = rsqrtf(var + 1e-3f);
  float4 gv = *(const float4*)(G + tid * 4);
  float4 bv = *(const float4*)(Bt + tid * 4);
  ushort4 ov;
  ov.x = f2b((v0 - mean) * rstd * gv.x + bv.x);
  ov.y = f2b((v1 - mean) * rstd * gv.y + bv.y);
  ov.z = f2b((v2 - mean) * rstd * gv.z + bv.z);
  ov.w = f2b((v3 - mean) * rstd * gv.w + bv.w);
  *(ushort4*)(O + (size_t)row * 1024 + tid * 4) = ov;
}

__global__ __launch_bounds__(256)
void ln_bf16_kernel(const u16* __restrict__ X, const float* __restrict__ G,
                    const float* __restrict__ Bt, u16* __restrict__ O) {
  const int row = blockIdx.x;
  const int tid = threadIdx.x;
  const u16* xr = X + (size_t)row * 1024;
  ushort4 xv = *(const ushort4*)(xr + tid * 4);
  float v0 = b2f(xv.x), v1 = b2f(xv.y), v2 = b2f(xv.z), v3 = b2f(xv.w);
  float s = v0 + v1 + v2 + v3;
  float q = v0 * v0 + v1 * v1 + v2 * v2 + v3 * v3;
  #pragma unroll
  for (int off = 32; off > 0; off >>= 1) {
    s += __shfl_down(s, off);
    q += __shfl_down(q, off);
  }
  __shared__ float red[8];
  int wave = tid >> 6, lane = tid & 63;
  if (lane == 0) { red[wave] = s; red[4 + wave] = q; }
  __syncthreads();
  s = red[0] + red[1] + red[2] + red[3];
  q = red[4] + red[5] + red[6] + red[7];
  float mean = s * (1.f / 1024.f);
  float var = q * (1.f / 1024.f) - mean * mean;
  float rstd = rsqrtf(var + 1e-3f);
  float4 gv = *(const float4*)(G + tid * 4);
  float4 bv = *(const float4*)(Bt + tid * 4);
  ushort4 ov;
  ov.x = f2b((v0 - mean) * rstd * gv.x + bv.x);
  ov.y = f2b((v1 - mean) * rstd * gv.y + bv.y);
  ov.z = f2b((v2 - mean) * rstd * gv.z + bv.z);
  ov.w = f2b((v3 - mean) * rstd * gv.w + bv.w);
  *(ushort4*)(O + (size_t)row * 1024 + tid * 4) = ov;
}

// ---------------- NT GEMM: A[M,K] * BT[N,K]^T, bf16 in, fp32 acc -------------
// 128x128 tile, BK=64. Round-8: 48 KiB LDS = A double-buffered (2x16K) +
// B SINGLE-buffered (16K) -> 3 blocks/CU (was 2 at 64 KiB; registers allow
// 3 waves/SIMD: 92 VGPR + 64 AGPR = 156 <= 170). The 3rd independent block
// fills the per-iter vmcnt stall -> MfmaUtil up.
// Per K-iter (proven R3/R6 schedule + one extra barrier for B reuse safety):
//   [top] vmcnt(0) (exactly tile t's 8 loads outstanding) + s_barrier
//   -> 16 fragment ds_read_b128 (A from buf p, B from the single buffer)
//   -> lgkmcnt(0) + s_barrier   (all waves' B-frag reads COMPLETE, so
//      B(t+1)'s async LDS writes cannot race them)
//   -> issue A(t+1)->buf p^1, B(t+1)->B buffer (fly under the MFMAs)
//   -> 32 MFMA.
// Row = 128B in LDS; 16B k-chunk slot XOR-swizzled with (row&7) (T2).
// Region-mapped XCD swizzle kept from R7 (neutral-to-positive, free).
// Epilogue reuses smem[0:8192) u16 for the C transpose.
// EPI 0: qkv 3-part bias; 1: bias+residual (bf16 out); 2: bias+GELU(fast);
// 3: bias+residual (fp32 out).
template <int EPI>
__global__ __launch_bounds__(256, 3)
void gemm_nt(const u16* __restrict__ A, const u16* __restrict__ BT,
             void* __restrict__ Cout,
             const float* __restrict__ bias0, const float* __restrict__ bias1,
             const float* __restrict__ bias2, const u16* __restrict__ resid,
             int M, int N, int K, int RA, int RB, int NRn) {
  __shared__ __align__(16) u16 smem[24576];     // 48 KiB: A0,A1,B
  const int tid = threadIdx.x;

  // region-mapped XCD swizzle
  const int xcd = blockIdx.x & 7;
  const int s_ = blockIdx.x >> 3;
  const int rm = xcd / NRn, rn = xcd - rm * NRn;
  const int lm = s_ / RB, ln = s_ - lm * RB;
  const int m0 = (rm * RA + lm) * 128;
  const int n0 = (rn * RB + ln) * 128;

  const int wave = tid >> 6, lane = tid & 63;
  const int wm = wave & 1, wn = wave >> 1;
  const int quad = lane >> 4, l16 = lane & 15;

  f32x4 acc[4][4];
  #pragma unroll
  for (int i = 0; i < 4; ++i)
    #pragma unroll
    for (int j = 0; j < 4; ++j) acc[i][j] = (f32x4){0.f, 0.f, 0.f, 0.f};

  // staging: thread tid covers row rowS (+32,+64,+96), stored slot = tid&7.
  // Stored slot s of row r holds logical k-chunk s ^ (r&7).
  const int rowS = tid >> 3;                    // 0..31
  const int swz = ((tid & 7) ^ ((tid >> 3) & 7)) * 8;   // source k-offset
  const u16* aB = A + (size_t)(m0 + rowS) * K + swz;
  const u16* bB = BT + (size_t)(n0 + rowS) * K + swz;
  const size_t rstep = (size_t)32 * K;          // 32 rows down

  const int nt = K >> 6;

  // issue the 4 global_load_lds for K-tile kt of A into A-buffer p
  auto stageA = [&](int p, int kt) {
    u16* aD = &smem[(u32)p * 8192 + (u32)tid * 8];
    const int k0 = kt * 64;
    #pragma unroll
    for (int cc = 0; cc < 4; ++cc)
      g2l16(aB + k0 + cc * rstep, aD + cc * 2048);
  };
  // issue the 4 global_load_lds for K-tile kt of B into the single B-buffer
  auto stageB = [&](int kt) {
    u16* bD = &smem[16384u + (u32)tid * 8];
    const int k0 = kt * 64;
    #pragma unroll
    for (int cc = 0; cc < 4; ++cc)
      g2l16(bB + k0 + cc * rstep, bD + cc * 2048);
  };

  stageA(0, 0); stageB(0);   // prologue: tile 0

  for (int t = 0; t < nt; ++t) {
    const int p = t & 1;
    // only tile t's 8 loads are outstanding here (t+1 not yet issued)
    asm volatile("s_waitcnt vmcnt(0)" ::: "memory");
    __builtin_amdgcn_s_barrier();
    const u16* As = &smem[(u32)p * 8192];
    const u16* Bs = &smem[16384u];

    bf16x8 aF[2][4], bF[2][4];
    #pragma unroll
    for (int ks = 0; ks < 2; ++ks) {
      // fragment row = wm*64+i*16+l16 -> row&7 = l16&7; logical chunk ks*4+quad
      const int sOff = (((ks * 4 + quad) ^ (l16 & 7)) * 8);
      #pragma unroll
      for (int i = 0; i < 4; ++i)
        aF[ks][i] = *(const bf16x8*)&As[(wm * 64 + i * 16 + l16) * 64 + sOff];
      #pragma unroll
      for (int j = 0; j < 4; ++j)
        bF[ks][j] = *(const bf16x8*)&Bs[(wn * 64 + j * 16 + l16) * 64 + sOff];
    }
    // all frag reads complete in-register before B(t+1) may overwrite B-buffer
    asm volatile("s_waitcnt lgkmcnt(0)" ::: "memory");
    __builtin_amdgcn_s_barrier();
    if (t + 1 < nt) { stageA(p ^ 1, t + 1); stageB(t + 1); }  // fly under MFMAs
    #pragma unroll
    for (int ks = 0; ks < 2; ++ks)
      #pragma unroll
      for (int i = 0; i < 4; ++i)
        #pragma unroll
        for (int j = 0; j < 4; ++j)
          acc[i][j] = __builtin_amdgcn_mfma_f32_16x16x32_bf16(
              aF[ks][i], bF[ks][j], acc[ks & 0 ? 0 : i][j], 0, 0, 0);
  }
  __syncthreads();   // K-loop reads done before epilogue overwrites smem

  // ---- epilogue: stage 64x128 halves through LDS (16B-chunk XOR swizzle),
  // then coalesced stores. C/D layout: col=lane&15, row=quad*4+reg (m89).
  #pragma unroll
  for (int half = 0; half < 2; ++half) {
    if (wm == half) {
      #pragma unroll
      for (int i = 0; i < 4; ++i) {
        const int fsw = (i * 4 + quad) & 7;     // (lrow>>2)&7
        #pragma unroll
        for (int j = 0; j < 4; ++j) {
          const int chunk = (wn * 8 + j * 2 + (l16 >> 3)) ^ fsw;
          const int base = chunk * 8 + (l16 & 7);
          #pragma unroll
          for (int rr = 0; rr < 4; ++rr) {
            const int lrow = i * 16 + quad * 4 + rr;
            smem[lrow * 128 + base] = f2b(acc[i][j][rr]);
          }
        }
      }
    }
    __syncthreads();
    #pragma unroll
    for (int s = 0; s < 4; ++s) {
      const int lrow = s * 16 + (tid >> 4);
      const int chunk = tid & 15;
      const int fsw = (lrow >> 2) & 7;
      bf16x8 cv = *(const bf16x8*)&smem[lrow * 128 + ((chunk ^ fsw) * 8)];
      const int gr = m0 + half * 64 + lrow;
      const int gc = n0 + chunk * 8;
      const float* bp_ = bias0;
      int cb = gc;
      if (EPI == 0) {
        const int selb = gc >> 10;
        bp_ = (selb == 0) ? bias0 : ((selb == 1) ? bias1 : bias2);
        cb = gc & 1023;
      }
      float4 bv0 = *(const float4*)(bp_ + cb);
      float4 bv1 = *(const float4*)(bp_ + cb + 4);
      float vv[8];
      #pragma unroll
      for (int e = 0; e < 8; ++e) {
        float be = (e < 4) ? ((const float*)&bv0)[e] : ((const float*)&bv1)[e - 4];
        vv[e] = b2f(((const u16*)&cv)[e]) + be;
      }
      if (EPI == 2) {
        #pragma unroll
        for (int e = 0; e < 8; ++e) vv[e] = gelu_fast(vv[e]);
      }
      if (EPI == 1 || EPI == 3) {
        bf16x8 rv = *(const bf16x8*)(resid + (size_t)gr * N + gc);
        #pragma unroll
        for (int e = 0; e < 8; ++e) vv[e] += b2f(((const u16*)&rv)[e]);
      }
      if (EPI == 3) {
        float4 o0 = {vv[0], vv[1], vv[2], vv[3]};
        float4 o1 = {vv[4], vv[5], vv[6], vv[7]};
        float* op = (float*)Cout + (size_t)gr * N + gc;
        *(float4*)op = o0;
        *(float4*)(op + 4) = o1;
      } else {
        bf16x8 ov;
        #pragma unroll
        for (int e = 0; e < 8; ++e) ((u16*)&ov)[e] = f2b(vv[e]);
        *(bf16x8*)((u16*)Cout + (size_t)gr * N + gc) = ov;
      }
    }
    __syncthreads();   // half-0 reads done before half-1 overwrites
  }
}

// ---------------- attention (no softmax!): M = scale * K^T V per (b,h) -------
// d2 split into 4 quarters (grid.y = 4) -> 512 blocks = 2/CU (R7 win, kept).
__global__ __launch_bounds__(256)
void attn_m_kernel(const u16* __restrict__ qkv, float* __restrict__ Mbuf) {
  const int bh = blockIdx.x;
  const int qtr = blockIdx.y;                   // d2 cols [qtr*16, qtr*16+16)
  const int b = bh >> 4, h = bh & 15;
  const u16* Kp = qkv + (size_t)b * 1024 * 3072 + 1024 + h * 64;
  const u16* Vp = Kp + 1024 + qtr * 16;
  __shared__ __align__(16) float Ks[64 * 64];
  __shared__ __align__(16) float Vs[64 * 20];   // stride 20: 16B-aligned rows
  const int tid = threadIdx.x;
  const int d1 = tid & 63, d2q = (tid >> 6) * 4;
  const int lr = tid >> 3, lc = (tid & 7) * 8;  // K staging: 32 rows x 8 cols
  const int vr = tid >> 2, vc = (tid & 3) * 4;  // V staging: 64 rows x 4 cols
  float acc[4];
  #pragma unroll
  for (int j = 0; j < 4; ++j) acc[j] = 0.f;
  for (int t0 = 0; t0 < 1024; t0 += 64) {
    __syncthreads();
    #pragma unroll
    for (int it = 0; it < 2; ++it) {
      int r = it * 32 + lr;
      const u16* ks = Kp + (size_t)(t0 + r) * 3072 + lc;
      ushort4 a0 = *(const ushort4*)ks;
      ushort4 a1 = *(const ushort4*)(ks + 4);
      float* kd = &Ks[r * 64 + lc];
      kd[0] = b2f(a0.x); kd[1] = b2f(a0.y); kd[2] = b2f(a0.z); kd[3] = b2f(a0.w);
      kd[4] = b2f(a1.x); kd[5] = b2f(a1.y); kd[6] = b2f(a1.z); kd[7] = b2f(a1.w);
    }
    {
      const u16* vs = Vp + (size_t)(t0 + vr) * 3072 + vc;
      ushort4 c0 = *(const ushort4*)vs;
      float4 vvw = {b2f(c0.x), b2f(c0.y), b2f(c0.z), b2f(c0.w)};
      *(float4*)&Vs[vr * 20 + vc] = vvw;
    }
    __syncthreads();
    #pragma unroll 8
    for (int tt = 0; tt < 64; ++tt) {
      float kv = Ks[tt * 64 + d1];
      float4 vv = *(const float4*)&Vs[tt * 20 + d2q];
      #pragma unroll
      for (int j = 0; j < 4; ++j) acc[j] += kv * ((const float*)&vv)[j];
    }
  }
  float4 o = {acc[0] * 0.03125f, acc[1] * 0.03125f,
              acc[2] * 0.03125f, acc[3] * 0.03125f};   // C^-0.5 = 1/32
  *(float4*)(Mbuf + (size_t)bh * 4096 + d1 * 64 + qtr * 16 + d2q) = o;
}

// heads = Q @ M, written directly in concat layout cat[b,t, h*64+d]
__global__ __launch_bounds__(256)
void attn_h_kernel(const u16* __restrict__ qkv, const float* __restrict__ Mbuf,
                   u16* __restrict__ cat) {
  const int bh = blockIdx.x;
  const int tch = blockIdx.y;
  const int b = bh >> 4, h = bh & 15;
  __shared__ __align__(16) float Ms[64 * 64];
  __shared__ __align__(16) float Qs[64 * 65];
  const int tid = threadIdx.x;
  const float* Msrc = Mbuf + (size_t)bh * 4096;
  #pragma unroll
  for (int i = 0; i < 16; ++i) Ms[i * 256 + tid] = Msrc[i * 256 + tid];
  const u16* Qp = qkv + (size_t)(b * 1024 + tch * 64) * 3072 + h * 64;
  {
    const int lr = tid >> 3, lc = (tid & 7) * 8;
    #pragma unroll
    for (int it = 0; it < 2; ++it) {
      int r = it * 32 + lr;
      const u16* qs = Qp + (size_t)r * 3072 + lc;
      ushort4 a0 = *(const ushort4*)qs;
      ushort4 a1 = *(const ushort4*)(qs + 4);
      float* qd = &Qs[r * 65 + lc];
      qd[0] = b2f(a0.x); qd[1] = b2f(a0.y); qd[2] = b2f(a0.z); qd[3] = b2f(a0.w);
      qd[4] = b2f(a1.x); qd[5] = b2f(a1.y); qd[6] = b2f(a1.z); qd[7] = b2f(a1.w);
    }
  }
  __syncthreads();
  const int tl = tid >> 2, db = (tid & 3) * 16;
  float acc[16];
  #pragma unroll
  for (int j = 0; j < 16; ++j) acc[j] = 0.f;
  #pragma unroll 4
  for (int k = 0; k < 64; ++k) {
    float qv = Qs[tl * 65 + k];
    #pragma unroll
    for (int m4 = 0; m4 < 4; ++m4) {
      float4 mv = *(const float4*)&Ms[k * 64 + db + m4 * 4];
      #pragma unroll
      for (int j = 0; j < 4; ++j) acc[m4 * 4 + j] += qv * ((const float*)&mv)[j];
    }
  }
  u16* Cp = cat + (size_t)(b * 1024 + tch * 64 + tl) * 1024 + h * 64 + db;
  ushort4 o0 = {f2b(acc[0]), f2b(acc[1]), f2b(acc[2]), f2b(acc[3])};
  ushort4 o1 = {f2b(acc[4]), f2b(acc[5]), f2b(acc[6]), f2b(acc[7])};
  ushort4 o2 = {f2b(acc[8]), f2b(acc[9]), f2b(acc[10]), f2b(acc[11])};
  ushort4 o3 = {f2b(acc[12]), f2b(acc[13]), f2b(acc[14]), f2b(acc[15])};
  *(ushort4*)(Cp + 0) = o0;
  *(ushort4*)(Cp + 4) = o1;
  *(ushort4*)(Cp + 8) = o2;
  *(ushort4*)(Cp + 12) = o3;
}

extern "C" void kernel_launch(void* const* d_in, const int* in_sizes, int n_in,
                              void* d_out, int out_size, void* d_ws, size_t ws_size,
                              hipStream_t stream) {
  (void)in_sizes; (void)n_in; (void)out_size; (void)ws_size;
  const float* x     = (const float*)d_in[0];
  const float* Wq    = (const float*)d_in[1];
  const float* bq    = (const float*)d_in[2];
  const float* Wk    = (const float*)d_in[3];
  const float* bk    = (const float*)d_in[4];
  const float* Wv    = (const float*)d_in[5];
  const float* bv    = (const float*)d_in[6];
  const float* Wp    = (const float*)d_in[7];
  const float* bp    = (const float*)d_in[8];
  const float* W1    = (const float*)d_in[9];
  const float* b1    = (const float*)d_in[10];
  const float* W2    = (const float*)d_in[11];
  const float* b2    = (const float*)d_in[12];
  const float* ln1w  = (const float*)d_in[13];
  const float* ln1b  = (const float*)d_in[14];
  const float* ln2w  = (const float*)d_in[15];
  const float* ln2b  = (const float*)d_in[16];

  char* ws = (char*)d_ws;
  u16* x1    = (u16*)(ws);                        // 16 MiB  [8192,1024] bf16
  u16* qkv   = (u16*)(ws + 16777216);             // 48 MiB  [8192,3072] bf16
  u16* cat   = (u16*)(ws + 67108864);             // 16 MiB  [8192,1024] bf16
  u16* yb    = (u16*)(ws + 83886080);             // 16 MiB  [8192,1024] bf16
  u16* x2    = (u16*)(ws + 100663296);            // 16 MiB  [8192,1024] bf16
  u16* WqkvT = (u16*)(ws + 117440512);            // 6 MiB   [3072,1024] bf16
  u16* WpT   = (u16*)(ws + 123731968);            // 2 MiB   [1024,1024] bf16
  u16* W1T   = (u16*)(ws + 125829120);            // 8 MiB   [4096,1024] bf16
  u16* W2T   = (u16*)(ws + 134217728);            // 8 MiB   [1024,4096] bf16
  float* Mb  = (float*)(ws + 142606336);          // 2 MiB   [128,64,64] fp32
  u16* hb    = (u16*)(ws + 16777216);             // 64 MiB, reuses dead qkv+cat

  repack_qkv_tiled<<<dim3(16, 48), 256, 0, stream>>>(Wq, Wk, Wv, WqkvT);
  transpose_tiled<<<dim3(32, 32), 256, 0, stream>>>(Wp, WpT, 1024, 1024);
  transpose_tiled<<<dim3(128, 32), 256, 0, stream>>>(W1, W1T, 4096, 1024);
  transpose_tiled<<<dim3(32, 128), 256, 0, stream>>>(W2, W2T, 1024, 4096);

  ln_f32_kernel<<<8192, 256, 0, stream>>>(x, ln1w, ln1b, x1);

  // 1-D grids; region-mapped XCD swizzle (RA x RB tile region per XCD,
  // NRm x NRn region layout with NRm*NRn = 8; RA*RB = gridDim/8):
  // QKV : 64x24 tiles -> regions 16x12, layout 4x2
  gemm_nt<0><<<1536, 256, 0, stream>>>(x1, WqkvT, qkv, bq, bk, bv, nullptr,
                                       8192, 3072, 1024, 16, 12, 2);
  attn_m_kernel<<<dim3(128, 4), 256, 0, stream>>>(qkv, Mb);
  attn_h_kernel<<<dim3(128, 16), 256, 0, stream>>>(qkv, Mb, cat);

  // proj : 64x8 tiles -> regions 8x8, layout 8x1
  gemm_nt<1><<<512, 256, 0, stream>>>(cat, WpT, yb, bp, nullptr, nullptr, x1,
                                      8192, 1024, 1024, 8, 8, 1);
  ln_bf16_kernel<<<8192, 256, 0, stream>>>(yb, ln2w, ln2b, x2);

  // FF1 : 64x32 tiles -> regions 16x16, layout 4x2
  gemm_nt<2><<<2048, 256, 0, stream>>>(x2, W1T, hb, b1, nullptr, nullptr, nullptr,
                                       8192, 4096, 1024, 16, 16, 2);
  // FF2 : 64x8 tiles -> regions 8x8, layout 8x1
  gemm_nt<3><<<512, 256, 0, stream>>>(hb, W2T, d_out, b2, nullptr, nullptr, x2,
                                      8192, 1024, 4096, 8, 8, 1);
}

// Round 10
// 442.147 us; speedup vs baseline: 1.0642x; 1.0642x over previous
//
#include <hip/hip_runtime.h>

typedef unsigned short u16;
typedef unsigned int u32;
typedef unsigned long long u64;
typedef __attribute__((ext_vector_type(8))) short bf16x8;
typedef __attribute__((ext_vector_type(4))) float f32x4;

__device__ __forceinline__ float b2f(u16 v) {
  union { u32 u; float f; } c; c.u = ((u32)v) << 16; return c.f;
}
__device__ __forceinline__ u16 f2b(float f) {
  union { float f; u32 u; } c; c.f = f;
  return (u16)((c.u + 0x7fffu + ((c.u >> 16) & 1u)) >> 16);
}

// async global->LDS, 16B per lane (global_load_lds_dwordx4).
__device__ __forceinline__ void g2l16(const u16* g, u16* l) {
  __builtin_amdgcn_global_load_lds(
      (const __attribute__((address_space(1))) u32*)g,
      (__attribute__((address_space(3))) u32*)l,
      16, 0, 0);
}

// tanh-form GELU: verified rounds 1-8 (absmax unchanged at 0.0625).
__device__ __forceinline__ float gelu_fast(float x) {
  float z2 = -1.5957691216057308f * x * (1.0f + 0.044715f * x * x);  // -2z
  z2 = fminf(fmaxf(z2, -30.f), 30.f);
  float t = __expf(z2);
  return x * __builtin_amdgcn_rcpf(1.0f + t);
}

// ---------------- LDS-tiled weight repacks (fp32 in -> bf16 out) -------------
__global__ __launch_bounds__(256)
void repack_qkv_tiled(const float* __restrict__ Wq, const float* __restrict__ Wk,
                      const float* __restrict__ Wv, u16* __restrict__ WT) {
  __shared__ u16 tile[64][65];
  const int sh = blockIdx.y, sel = sh >> 4, h = sh & 15;
  const float* W = (sel == 0) ? Wq : ((sel == 1) ? Wk : Wv);
  const int k0 = blockIdx.x * 64;
  {
    const int d = threadIdx.x & 63, r = threadIdx.x >> 6;
    #pragma unroll
    for (int i = 0; i < 16; ++i) {
      int k = r * 16 + i;
      tile[k][d] = f2b(W[(size_t)h * 65536 + (size_t)(k0 + k) * 64 + d]);
    }
  }
  __syncthreads();
  {
    const int k = threadIdx.x & 63, dd = threadIdx.x >> 6;
    #pragma unroll
    for (int i = 0; i < 16; ++i) {
      int d2 = dd * 16 + i;
      WT[((size_t)sel * 1024 + h * 64 + d2) * 1024 + k0 + k] = tile[k][d2];
    }
  }
}

__global__ __launch_bounds__(256)
void transpose_tiled(const float* __restrict__ W, u16* __restrict__ WT,
                     int N, int K) {
  __shared__ u16 tile[32][33];
  const int bx = blockIdx.x * 32;   // n
  const int by = blockIdx.y * 32;   // k
  const int tx = threadIdx.x & 31, ty = threadIdx.x >> 5;
  #pragma unroll
  for (int i = 0; i < 4; ++i) {
    int k = ty + i * 8;
    tile[k][tx] = f2b(W[(size_t)(by + k) * N + bx + tx]);
  }
  __syncthreads();
  #pragma unroll
  for (int i = 0; i < 4; ++i) {
    int n = ty + i * 8;
    WT[(size_t)(bx + n) * K + by + tx] = tile[tx][n];
  }
}

// ---------------- LayerNorm (C=1024, EPS=1e-3), bf16 out ----------------
__global__ __launch_bounds__(256)
void ln_f32_kernel(const float* __restrict__ X, const float* __restrict__ G,
                   const float* __restrict__ Bt, u16* __restrict__ O) {
  const int row = blockIdx.x;
  const int tid = threadIdx.x;
  const float* xr = X + (size_t)row * 1024;
  float4 xv = *(const float4*)(xr + tid * 4);
  float v0 = xv.x, v1 = xv.y, v2 = xv.z, v3 = xv.w;
  float s = v0 + v1 + v2 + v3;
  float q = v0 * v0 + v1 * v1 + v2 * v2 + v3 * v3;
  #pragma unroll
  for (int off = 32; off > 0; off >>= 1) {
    s += __shfl_down(s, off);
    q += __shfl_down(q, off);
  }
  __shared__ float red[8];
  int wave = tid >> 6, lane = tid & 63;
  if (lane == 0) { red[wave] = s; red[4 + wave] = q; }
  __syncthreads();
  s = red[0] + red[1] + red[2] + red[3];
  q = red[4] + red[5] + red[6] + red[7];
  float mean = s * (1.f / 1024.f);
  float var = q * (1.f / 1024.f) - mean * mean;
  float rstd = rsqrtf(var + 1e-3f);
  float4 gv = *(const float4*)(G + tid * 4);
  float4 bv = *(const float4*)(Bt + tid * 4);
  ushort4 ov;
  ov.x = f2b((v0 - mean) * rstd * gv.x + bv.x);
  ov.y = f2b((v1 - mean) * rstd * gv.y + bv.y);
  ov.z = f2b((v2 - mean) * rstd * gv.z + bv.z);
  ov.w = f2b((v3 - mean) * rstd * gv.w + bv.w);
  *(ushort4*)(O + (size_t)row * 1024 + tid * 4) = ov;
}

__global__ __launch_bounds__(256)
void ln_bf16_kernel(const u16* __restrict__ X, const float* __restrict__ G,
                    const float* __restrict__ Bt, u16* __restrict__ O) {
  const int row = blockIdx.x;
  const int tid = threadIdx.x;
  const u16* xr = X + (size_t)row * 1024;
  ushort4 xv = *(const ushort4*)(xr + tid * 4);
  float v0 = b2f(xv.x), v1 = b2f(xv.y), v2 = b2f(xv.z), v3 = b2f(xv.w);
  float s = v0 + v1 + v2 + v3;
  float q = v0 * v0 + v1 * v1 + v2 * v2 + v3 * v3;
  #pragma unroll
  for (int off = 32; off > 0; off >>= 1) {
    s += __shfl_down(s, off);
    q += __shfl_down(q, off);
  }
  __shared__ float red[8];
  int wave = tid >> 6, lane = tid & 63;
  if (lane == 0) { red[wave] = s; red[4 + wave] = q; }
  __syncthreads();
  s = red[0] + red[1] + red[2] + red[3];
  q = red[4] + red[5] + red[6] + red[7];
  float mean = s * (1.f / 1024.f);
  float var = q * (1.f / 1024.f) - mean * mean;
  float rstd = rsqrtf(var + 1e-3f);
  float4 gv = *(const float4*)(G + tid * 4);
  float4 bv = *(const float4*)(Bt + tid * 4);
  ushort4 ov;
  ov.x = f2b((v0 - mean) * rstd * gv.x + bv.x);
  ov.y = f2b((v1 - mean) * rstd * gv.y + bv.y);
  ov.z = f2b((v2 - mean) * rstd * gv.z + bv.z);
  ov.w = f2b((v3 - mean) * rstd * gv.w + bv.w);
  *(ushort4*)(O + (size_t)row * 1024 + tid * 4) = ov;
}

// ---------------- shared GEMM epilogue (LDS transpose + fused ops) -----------
// EPI 0: qkv 3-part bias; 1: bias+residual (bf16 out); 2: bias+GELU(fast);
// 3: bias+residual (fp32 out).
template <int EPI>
__device__ __forceinline__ void gemm_epilogue(
    u16* smem, f32x4 (&acc)[4][4], void* Cout,
    const float* bias0, const float* bias1, const float* bias2,
    const u16* resid, int N, int m0, int n0,
    int tid, int wm, int wn, int quad, int l16) {
  #pragma unroll
  for (int half = 0; half < 2; ++half) {
    if (wm == half) {
      #pragma unroll
      for (int i = 0; i < 4; ++i) {
        const int fsw = (i * 4 + quad) & 7;     // (lrow>>2)&7
        #pragma unroll
        for (int j = 0; j < 4; ++j) {
          const int chunk = (wn * 8 + j * 2 + (l16 >> 3)) ^ fsw;
          const int base = chunk * 8 + (l16 & 7);
          #pragma unroll
          for (int rr = 0; rr < 4; ++rr) {
            const int lrow = i * 16 + quad * 4 + rr;
            smem[lrow * 128 + base] = f2b(acc[i][j][rr]);
          }
        }
      }
    }
    __syncthreads();
    #pragma unroll
    for (int s = 0; s < 4; ++s) {
      const int lrow = s * 16 + (tid >> 4);
      const int chunk = tid & 15;
      const int fsw = (lrow >> 2) & 7;
      bf16x8 cv = *(const bf16x8*)&smem[lrow * 128 + ((chunk ^ fsw) * 8)];
      const int gr = m0 + half * 64 + lrow;
      const int gc = n0 + chunk * 8;
      const float* bp_ = bias0;
      int cb = gc;
      if (EPI == 0) {
        const int selb = gc >> 10;
        bp_ = (selb == 0) ? bias0 : ((selb == 1) ? bias1 : bias2);
        cb = gc & 1023;
      }
      float4 bv0 = *(const float4*)(bp_ + cb);
      float4 bv1 = *(const float4*)(bp_ + cb + 4);
      float vv[8];
      #pragma unroll
      for (int e = 0; e < 8; ++e) {
        float be = (e < 4) ? ((const float*)&bv0)[e] : ((const float*)&bv1)[e - 4];
        vv[e] = b2f(((const u16*)&cv)[e]) + be;
      }
      if (EPI == 2) {
        #pragma unroll
        for (int e = 0; e < 8; ++e) vv[e] = gelu_fast(vv[e]);
      }
      if (EPI == 1 || EPI == 3) {
        bf16x8 rv = *(const bf16x8*)(resid + (size_t)gr * N + gc);
        #pragma unroll
        for (int e = 0; e < 8; ++e) vv[e] += b2f(((const u16*)&rv)[e]);
      }
      if (EPI == 3) {
        float4 o0 = {vv[0], vv[1], vv[2], vv[3]};
        float4 o1 = {vv[4], vv[5], vv[6], vv[7]};
        float* op = (float*)Cout + (size_t)gr * N + gc;
        *(float4*)op = o0;
        *(float4*)(op + 4) = o1;
      } else {
        bf16x8 ov;
        #pragma unroll
        for (int e = 0; e < 8; ++e) ((u16*)&ov)[e] = f2b(vv[e]);
        *(bf16x8*)((u16*)Cout + (size_t)gr * N + gc) = ov;
      }
    }
    __syncthreads();   // half-0 reads done before half-1 overwrites
  }
}

// ---------------- GEMM variant 2: 64 KiB full double-buffer (R7 proven) -----
// For 512-block launches (proj, FF2): grid caps residency at 2/CU, so the
// 64 KiB / 1-barrier-per-iter schedule is optimal (R8's extra barrier was
// pure cost here). K-loop: vmcnt(0)+barrier -> 16 frag ds_read -> stage(t+1)
// -> 32 MFMA.
template <int EPI>
__global__ __launch_bounds__(256)
void gemm_nt2(const u16* __restrict__ A, const u16* __restrict__ BT,
              void* __restrict__ Cout,
              const float* __restrict__ bias0, const float* __restrict__ bias1,
              const float* __restrict__ bias2, const u16* __restrict__ resid,
              int M, int N, int K, int RA, int RB, int NRn) {
  __shared__ __align__(16) u16 smem[32768];     // 64 KiB: A0,A1,B0,B1
  const int tid = threadIdx.x;

  const int xcd = blockIdx.x & 7;
  const int s_ = blockIdx.x >> 3;
  const int rm = xcd / NRn, rn = xcd - rm * NRn;
  const int lm = s_ / RB, ln = s_ - lm * RB;
  const int m0 = (rm * RA + lm) * 128;
  const int n0 = (rn * RB + ln) * 128;

  const int wave = tid >> 6, lane = tid & 63;
  const int wm = wave & 1, wn = wave >> 1;
  const int quad = lane >> 4, l16 = lane & 15;

  f32x4 acc[4][4];
  #pragma unroll
  for (int i = 0; i < 4; ++i)
    #pragma unroll
    for (int j = 0; j < 4; ++j) acc[i][j] = (f32x4){0.f, 0.f, 0.f, 0.f};

  const int rowS = tid >> 3;
  const int swz = ((tid & 7) ^ ((tid >> 3) & 7)) * 8;
  const u16* aB = A + (size_t)(m0 + rowS) * K + swz;
  const u16* bB = BT + (size_t)(n0 + rowS) * K + swz;
  const size_t rstep = (size_t)32 * K;

  const int nt = K >> 6;

  auto stage = [&](int p, int kt) {
    u16* aD = &smem[(u32)p * 8192 + (u32)tid * 8];
    u16* bD = &smem[16384u + (u32)p * 8192 + (u32)tid * 8];
    const int k0 = kt * 64;
    #pragma unroll
    for (int cc = 0; cc < 4; ++cc) {
      g2l16(aB + k0 + cc * rstep, aD + cc * 2048);
      g2l16(bB + k0 + cc * rstep, bD + cc * 2048);
    }
  };

  stage(0, 0);

  for (int t = 0; t < nt; ++t) {
    const int p = t & 1;
    asm volatile("s_waitcnt vmcnt(0)" ::: "memory");
    __builtin_amdgcn_s_barrier();
    const u16* As = &smem[(u32)p * 8192];
    const u16* Bs = &smem[16384u + (u32)p * 8192];

    bf16x8 aF[2][4], bF[2][4];
    #pragma unroll
    for (int ks = 0; ks < 2; ++ks) {
      const int sOff = (((ks * 4 + quad) ^ (l16 & 7)) * 8);
      #pragma unroll
      for (int i = 0; i < 4; ++i)
        aF[ks][i] = *(const bf16x8*)&As[(wm * 64 + i * 16 + l16) * 64 + sOff];
      #pragma unroll
      for (int j = 0; j < 4; ++j)
        bF[ks][j] = *(const bf16x8*)&Bs[(wn * 64 + j * 16 + l16) * 64 + sOff];
    }
    if (t + 1 < nt) stage(p ^ 1, t + 1);   // prefetch flies under the MFMAs
    #pragma unroll
    for (int ks = 0; ks < 2; ++ks)
      #pragma unroll
      for (int i = 0; i < 4; ++i)
        #pragma unroll
        for (int j = 0; j < 4; ++j)
          acc[i][j] = __builtin_amdgcn_mfma_f32_16x16x32_bf16(
              aF[ks][i], bF[ks][j], acc[i][j], 0, 0, 0);
  }
  __syncthreads();
  gemm_epilogue<EPI>(smem, acc, Cout, bias0, bias1, bias2, resid, N, m0, n0,
                     tid, wm, wn, quad, l16);
}

// ---------------- GEMM variant 3: 48 KiB, 3 blocks/CU (R8-verified) ---------
// For >=1536-block launches (QKV, FF1): A double-buffered (2x16K) + B single
// (16K) -> 3 blocks/CU (registers: 84 VGPR + 64 AGPR <= 170 for 3 waves/SIMD).
// Schedule EXACTLY as hardware-verified in R8 (no counted-lgkmcnt tricks):
//   [top] vmcnt(0) + s_barrier
//   -> 16 fragment ds_read_b128
//   -> lgkmcnt(0) + s_barrier  (all waves' frag reads complete, so B(t+1)'s
//      async LDS writes cannot race the single B buffer)
//   -> issue A(t+1)->buf p^1 and B(t+1)->B buffer (fly under the MFMAs)
//   -> 32 MFMA.
template <int EPI>
__global__ __launch_bounds__(256, 3)
void gemm_nt3(const u16* __restrict__ A, const u16* __restrict__ BT,
              void* __restrict__ Cout,
              const float* __restrict__ bias0, const float* __restrict__ bias1,
              const float* __restrict__ bias2, const u16* __restrict__ resid,
              int M, int N, int K, int RA, int RB, int NRn) {
  __shared__ __align__(16) u16 smem[24576];     // 48 KiB: A0,A1,B
  const int tid = threadIdx.x;

  const int xcd = blockIdx.x & 7;
  const int s_ = blockIdx.x >> 3;
  const int rm = xcd / NRn, rn = xcd - rm * NRn;
  const int lm = s_ / RB, ln = s_ - lm * RB;
  const int m0 = (rm * RA + lm) * 128;
  const int n0 = (rn * RB + ln) * 128;

  const int wave = tid >> 6, lane = tid & 63;
  const int wm = wave & 1, wn = wave >> 1;
  const int quad = lane >> 4, l16 = lane & 15;

  f32x4 acc[4][4];
  #pragma unroll
  for (int i = 0; i < 4; ++i)
    #pragma unroll
    for (int j = 0; j < 4; ++j) acc[i][j] = (f32x4){0.f, 0.f, 0.f, 0.f};

  const int rowS = tid >> 3;
  const int swz = ((tid & 7) ^ ((tid >> 3) & 7)) * 8;
  const u16* aB = A + (size_t)(m0 + rowS) * K + swz;
  const u16* bB = BT + (size_t)(n0 + rowS) * K + swz;
  const size_t rstep = (size_t)32 * K;

  const int nt = K >> 6;

  auto stageA = [&](int p, int kt) {
    u16* aD = &smem[(u32)p * 8192 + (u32)tid * 8];
    const int k0 = kt * 64;
    #pragma unroll
    for (int cc = 0; cc < 4; ++cc)
      g2l16(aB + k0 + cc * rstep, aD + cc * 2048);
  };
  auto stageB = [&](int kt) {
    u16* bD = &smem[16384u + (u32)tid * 8];
    const int k0 = kt * 64;
    #pragma unroll
    for (int cc = 0; cc < 4; ++cc)
      g2l16(bB + k0 + cc * rstep, bD + cc * 2048);
  };

  stageA(0, 0); stageB(0);   // prologue

  for (int t = 0; t < nt; ++t) {
    const int p = t & 1;
    // exactly tile t's 8 loads outstanding (t+1 not yet issued)
    asm volatile("s_waitcnt vmcnt(0)" ::: "memory");
    __builtin_amdgcn_s_barrier();
    const u16* As = &smem[(u32)p * 8192];
    const u16* Bs = &smem[16384u];

    bf16x8 aF[2][4], bF[2][4];
    #pragma unroll
    for (int ks = 0; ks < 2; ++ks) {
      const int sOff = (((ks * 4 + quad) ^ (l16 & 7)) * 8);
      #pragma unroll
      for (int j = 0; j < 4; ++j)
        bF[ks][j] = *(const bf16x8*)&Bs[(wn * 64 + j * 16 + l16) * 64 + sOff];
      #pragma unroll
      for (int i = 0; i < 4; ++i)
        aF[ks][i] = *(const bf16x8*)&As[(wm * 64 + i * 16 + l16) * 64 + sOff];
    }
    // all frag reads complete in-register before B(t+1) may overwrite B-buffer
    asm volatile("s_waitcnt lgkmcnt(0)" ::: "memory");
    __builtin_amdgcn_s_barrier();
    if (t + 1 < nt) { stageA(p ^ 1, t + 1); stageB(t + 1); }  // fly under MFMAs
    #pragma unroll
    for (int ks = 0; ks < 2; ++ks)
      #pragma unroll
      for (int i = 0; i < 4; ++i)
        #pragma unroll
        for (int j = 0; j < 4; ++j)
          acc[i][j] = __builtin_amdgcn_mfma_f32_16x16x32_bf16(
              aF[ks][i], bF[ks][j], acc[i][j], 0, 0, 0);
  }
  __syncthreads();
  gemm_epilogue<EPI>(smem, acc, Cout, bias0, bias1, bias2, resid, N, m0, n0,
                     tid, wm, wn, quad, l16);
}

// ---------------- attention (no softmax!): M = scale * K^T V per (b,h) -------
// d2 split into 4 quarters (grid.y = 4) -> 512 blocks = 2/CU (R7 win, kept).
__global__ __launch_bounds__(256)
void attn_m_kernel(const u16* __restrict__ qkv, float* __restrict__ Mbuf) {
  const int bh = blockIdx.x;
  const int qtr = blockIdx.y;                   // d2 cols [qtr*16, qtr*16+16)
  const int b = bh >> 4, h = bh & 15;
  const u16* Kp = qkv + (size_t)b * 1024 * 3072 + 1024 + h * 64;
  const u16* Vp = Kp + 1024 + qtr * 16;
  __shared__ __align__(16) float Ks[64 * 64];
  __shared__ __align__(16) float Vs[64 * 20];   // stride 20: 16B-aligned rows
  const int tid = threadIdx.x;
  const int d1 = tid & 63, d2q = (tid >> 6) * 4;
  const int lr = tid >> 3, lc = (tid & 7) * 8;  // K staging: 32 rows x 8 cols
  const int vr = tid >> 2, vc = (tid & 3) * 4;  // V staging: 64 rows x 4 cols
  float acc[4];
  #pragma unroll
  for (int j = 0; j < 4; ++j) acc[j] = 0.f;
  for (int t0 = 0; t0 < 1024; t0 += 64) {
    __syncthreads();
    #pragma unroll
    for (int it = 0; it < 2; ++it) {
      int r = it * 32 + lr;
      const u16* ks = Kp + (size_t)(t0 + r) * 3072 + lc;
      ushort4 a0 = *(const ushort4*)ks;
      ushort4 a1 = *(const ushort4*)(ks + 4);
      float* kd = &Ks[r * 64 + lc];
      kd[0] = b2f(a0.x); kd[1] = b2f(a0.y); kd[2] = b2f(a0.z); kd[3] = b2f(a0.w);
      kd[4] = b2f(a1.x); kd[5] = b2f(a1.y); kd[6] = b2f(a1.z); kd[7] = b2f(a1.w);
    }
    {
      const u16* vs = Vp + (size_t)(t0 + vr) * 3072 + vc;
      ushort4 c0 = *(const ushort4*)vs;
      float4 vvw = {b2f(c0.x), b2f(c0.y), b2f(c0.z), b2f(c0.w)};
      *(float4*)&Vs[vr * 20 + vc] = vvw;
    }
    __syncthreads();
    #pragma unroll 8
    for (int tt = 0; tt < 64; ++tt) {
      float kv = Ks[tt * 64 + d1];
      float4 vv = *(const float4*)&Vs[tt * 20 + d2q];
      #pragma unroll
      for (int j = 0; j < 4; ++j) acc[j] += kv * ((const float*)&vv)[j];
    }
  }
  float4 o = {acc[0] * 0.03125f, acc[1] * 0.03125f,
              acc[2] * 0.03125f, acc[3] * 0.03125f};   // C^-0.5 = 1/32
  *(float4*)(Mbuf + (size_t)bh * 4096 + d1 * 64 + qtr * 16 + d2q) = o;
}

// heads = Q @ M, written directly in concat layout cat[b,t, h*64+d]
__global__ __launch_bounds__(256)
void attn_h_kernel(const u16* __restrict__ qkv, const float* __restrict__ Mbuf,
                   u16* __restrict__ cat) {
  const int bh = blockIdx.x;
  const int tch = blockIdx.y;
  const int b = bh >> 4, h = bh & 15;
  __shared__ __align__(16) float Ms[64 * 64];
  __shared__ __align__(16) float Qs[64 * 65];
  const int tid = threadIdx.x;
  const float* Msrc = Mbuf + (size_t)bh * 4096;
  #pragma unroll
  for (int i = 0; i < 16; ++i) Ms[i * 256 + tid] = Msrc[i * 256 + tid];
  const u16* Qp = qkv + (size_t)(b * 1024 + tch * 64) * 3072 + h * 64;
  {
    const int lr = tid >> 3, lc = (tid & 7) * 8;
    #pragma unroll
    for (int it = 0; it < 2; ++it) {
      int r = it * 32 + lr;
      const u16* qs = Qp + (size_t)r * 3072 + lc;
      ushort4 a0 = *(const ushort4*)qs;
      ushort4 a1 = *(const ushort4*)(qs + 4);
      float* qd = &Qs[r * 65 + lc];
      qd[0] = b2f(a0.x); qd[1] = b2f(a0.y); qd[2] = b2f(a0.z); qd[3] = b2f(a0.w);
      qd[4] = b2f(a1.x); qd[5] = b2f(a1.y); qd[6] = b2f(a1.z); qd[7] = b2f(a1.w);
    }
  }
  __syncthreads();
  const int tl = tid >> 2, db = (tid & 3) * 16;
  float acc[16];
  #pragma unroll
  for (int j = 0; j < 16; ++j) acc[j] = 0.f;
  #pragma unroll 4
  for (int k = 0; k < 64; ++k) {
    float qv = Qs[tl * 65 + k];
    #pragma unroll
    for (int m4 = 0; m4 < 4; ++m4) {
      float4 mv = *(const float4*)&Ms[k * 64 + db + m4 * 4];
      #pragma unroll
      for (int j = 0; j < 4; ++j) acc[m4 * 4 + j] += qv * ((const float*)&mv)[j];
    }
  }
  u16* Cp = cat + (size_t)(b * 1024 + tch * 64 + tl) * 1024 + h * 64 + db;
  ushort4 o0 = {f2b(acc[0]), f2b(acc[1]), f2b(acc[2]), f2b(acc[3])};
  ushort4 o1 = {f2b(acc[4]), f2b(acc[5]), f2b(acc[6]), f2b(acc[7])};
  ushort4 o2 = {f2b(acc[8]), f2b(acc[9]), f2b(acc[10]), f2b(acc[11])};
  ushort4 o3 = {f2b(acc[12]), f2b(acc[13]), f2b(acc[14]), f2b(acc[15])};
  *(ushort4*)(Cp + 0) = o0;
  *(ushort4*)(Cp + 4) = o1;
  *(ushort4*)(Cp + 8) = o2;
  *(ushort4*)(Cp + 12) = o3;
}

extern "C" void kernel_launch(void* const* d_in, const int* in_sizes, int n_in,
                              void* d_out, int out_size, void* d_ws, size_t ws_size,
                              hipStream_t stream) {
  (void)in_sizes; (void)n_in; (void)out_size; (void)ws_size;
  const float* x     = (const float*)d_in[0];
  const float* Wq    = (const float*)d_in[1];
  const float* bq    = (const float*)d_in[2];
  const float* Wk    = (const float*)d_in[3];
  const float* bk    = (const float*)d_in[4];
  const float* Wv    = (const float*)d_in[5];
  const float* bv    = (const float*)d_in[6];
  const float* Wp    = (const float*)d_in[7];
  const float* bp    = (const float*)d_in[8];
  const float* W1    = (const float*)d_in[9];
  const float* b1    = (const float*)d_in[10];
  const float* W2    = (const float*)d_in[11];
  const float* b2    = (const float*)d_in[12];
  const float* ln1w  = (const float*)d_in[13];
  const float* ln1b  = (const float*)d_in[14];
  const float* ln2w  = (const float*)d_in[15];
  const float* ln2b  = (const float*)d_in[16];

  char* ws = (char*)d_ws;
  u16* x1    = (u16*)(ws);                        // 16 MiB  [8192,1024] bf16
  u16* qkv   = (u16*)(ws + 16777216);             // 48 MiB  [8192,3072] bf16
  u16* cat   = (u16*)(ws + 67108864);             // 16 MiB  [8192,1024] bf16
  u16* yb    = (u16*)(ws + 83886080);             // 16 MiB  [8192,1024] bf16
  u16* x2    = (u16*)(ws + 100663296);            // 16 MiB  [8192,1024] bf16
  u16* WqkvT = (u16*)(ws + 117440512);            // 6 MiB   [3072,1024] bf16
  u16* WpT   = (u16*)(ws + 123731968);            // 2 MiB   [1024,1024] bf16
  u16* W1T   = (u16*)(ws + 125829120);            // 8 MiB   [4096,1024] bf16
  u16* W2T   = (u16*)(ws + 134217728);            // 8 MiB   [1024,4096] bf16
  float* Mb  = (float*)(ws + 142606336);          // 2 MiB   [128,64,64] fp32
  u16* hb    = (u16*)(ws + 16777216);             // 64 MiB, reuses dead qkv+cat

  repack_qkv_tiled<<<dim3(16, 48), 256, 0, stream>>>(Wq, Wk, Wv, WqkvT);
  transpose_tiled<<<dim3(32, 32), 256, 0, stream>>>(Wp, WpT, 1024, 1024);
  transpose_tiled<<<dim3(128, 32), 256, 0, stream>>>(W1, W1T, 4096, 1024);
  transpose_tiled<<<dim3(32, 128), 256, 0, stream>>>(W2, W2T, 1024, 4096);

  ln_f32_kernel<<<8192, 256, 0, stream>>>(x, ln1w, ln1b, x1);

  // QKV : 1536 blocks (6/CU grid) -> 3-buffer variant; regions 16x12, 4x2
  gemm_nt3<0><<<1536, 256, 0, stream>>>(x1, WqkvT, qkv, bq, bk, bv, nullptr,
                                        8192, 3072, 1024, 16, 12, 2);
  attn_m_kernel<<<dim3(128, 4), 256, 0, stream>>>(qkv, Mb);
  attn_h_kernel<<<dim3(128, 16), 256, 0, stream>>>(qkv, Mb, cat);

  // proj : 512 blocks (2/CU grid cap) -> 64 KiB dbuf variant; regions 8x8, 8x1
  gemm_nt2<1><<<512, 256, 0, stream>>>(cat, WpT, yb, bp, nullptr, nullptr, x1,
                                       8192, 1024, 1024, 8, 8, 1);
  ln_bf16_kernel<<<8192, 256, 0, stream>>>(yb, ln2w, ln2b, x2);

  // FF1 : 2048 blocks (8/CU grid) -> 3-buffer variant; regions 16x16, 4x2
  gemm_nt3<2><<<2048, 256, 0, stream>>>(x2, W1T, hb, b1, nullptr, nullptr, nullptr,
                                        8192, 4096, 1024, 16, 16, 2);
  // FF2 : 512 blocks (2/CU grid cap) -> 64 KiB dbuf variant; regions 8x8, 8x1
  gemm_nt2<3><<<512, 256, 0, stream>>>(hb, W2T, d_out, b2, nullptr, nullptr, x2,
                                       8192, 1024, 4096, 8, 8, 1);
}

// Round 11
// 441.558 us; speedup vs baseline: 1.0656x; 1.0013x over previous
//
#include <hip/hip_runtime.h>

typedef unsigned short u16;
typedef unsigned int u32;
typedef unsigned long long u64;
typedef __attribute__((ext_vector_type(8))) short bf16x8;
typedef __attribute__((ext_vector_type(4))) float f32x4;

__device__ __forceinline__ float b2f(u16 v) {
  union { u32 u; float f; } c; c.u = ((u32)v) << 16; return c.f;
}
__device__ __forceinline__ u16 f2b(float f) {
  union { float f; u32 u; } c; c.f = f;
  return (u16)((c.u + 0x7fffu + ((c.u >> 16) & 1u)) >> 16);
}

// async global->LDS, 16B per lane (global_load_lds_dwordx4).
__device__ __forceinline__ void g2l16(const u16* g, u16* l) {
  __builtin_amdgcn_global_load_lds(
      (const __attribute__((address_space(1))) u32*)g,
      (__attribute__((address_space(3))) u32*)l,
      16, 0, 0);
}

// tanh-form GELU: verified rounds 1-10 (absmax unchanged at 0.0625).
__device__ __forceinline__ float gelu_fast(float x) {
  float z2 = -1.5957691216057308f * x * (1.0f + 0.044715f * x * x);  // -2z
  z2 = fminf(fmaxf(z2, -30.f), 30.f);
  float t = __expf(z2);
  return x * __builtin_amdgcn_rcpf(1.0f + t);
}

// ---------------- LDS-tiled weight repacks (fp32 in -> bf16 out) -------------
__global__ __launch_bounds__(256)
void repack_qkv_tiled(const float* __restrict__ Wq, const float* __restrict__ Wk,
                      const float* __restrict__ Wv, u16* __restrict__ WT) {
  __shared__ u16 tile[64][65];
  const int sh = blockIdx.y, sel = sh >> 4, h = sh & 15;
  const float* W = (sel == 0) ? Wq : ((sel == 1) ? Wk : Wv);
  const int k0 = blockIdx.x * 64;
  {
    const int d = threadIdx.x & 63, r = threadIdx.x >> 6;
    #pragma unroll
    for (int i = 0; i < 16; ++i) {
      int k = r * 16 + i;
      tile[k][d] = f2b(W[(size_t)h * 65536 + (size_t)(k0 + k) * 64 + d]);
    }
  }
  __syncthreads();
  {
    const int k = threadIdx.x & 63, dd = threadIdx.x >> 6;
    #pragma unroll
    for (int i = 0; i < 16; ++i) {
      int d2 = dd * 16 + i;
      WT[((size_t)sel * 1024 + h * 64 + d2) * 1024 + k0 + k] = tile[k][d2];
    }
  }
}

__global__ __launch_bounds__(256)
void transpose_tiled(const float* __restrict__ W, u16* __restrict__ WT,
                     int N, int K) {
  __shared__ u16 tile[32][33];
  const int bx = blockIdx.x * 32;   // n
  const int by = blockIdx.y * 32;   // k
  const int tx = threadIdx.x & 31, ty = threadIdx.x >> 5;
  #pragma unroll
  for (int i = 0; i < 4; ++i) {
    int k = ty + i * 8;
    tile[k][tx] = f2b(W[(size_t)(by + k) * N + bx + tx]);
  }
  __syncthreads();
  #pragma unroll
  for (int i = 0; i < 4; ++i) {
    int n = ty + i * 8;
    WT[(size_t)(bx + n) * K + by + tx] = tile[tx][n];
  }
}

// ---------------- LayerNorm (C=1024, EPS=1e-3), bf16 out ----------------
__global__ __launch_bounds__(256)
void ln_f32_kernel(const float* __restrict__ X, const float* __restrict__ G,
                   const float* __restrict__ Bt, u16* __restrict__ O) {
  const int row = blockIdx.x;
  const int tid = threadIdx.x;
  const float* xr = X + (size_t)row * 1024;
  float4 xv = *(const float4*)(xr + tid * 4);
  float v0 = xv.x, v1 = xv.y, v2 = xv.z, v3 = xv.w;
  float s = v0 + v1 + v2 + v3;
  float q = v0 * v0 + v1 * v1 + v2 * v2 + v3 * v3;
  #pragma unroll
  for (int off = 32; off > 0; off >>= 1) {
    s += __shfl_down(s, off);
    q += __shfl_down(q, off);
  }
  __shared__ float red[8];
  int wave = tid >> 6, lane = tid & 63;
  if (lane == 0) { red[wave] = s; red[4 + wave] = q; }
  __syncthreads();
  s = red[0] + red[1] + red[2] + red[3];
  q = red[4] + red[5] + red[6] + red[7];
  float mean = s * (1.f / 1024.f);
  float var = q * (1.f / 1024.f) - mean * mean;
  float rstd = rsqrtf(var + 1e-3f);
  float4 gv = *(const float4*)(G + tid * 4);
  float4 bv = *(const float4*)(Bt + tid * 4);
  ushort4 ov;
  ov.x = f2b((v0 - mean) * rstd * gv.x + bv.x);
  ov.y = f2b((v1 - mean) * rstd * gv.y + bv.y);
  ov.z = f2b((v2 - mean) * rstd * gv.z + bv.z);
  ov.w = f2b((v3 - mean) * rstd * gv.w + bv.w);
  *(ushort4*)(O + (size_t)row * 1024 + tid * 4) = ov;
}

__global__ __launch_bounds__(256)
void ln_bf16_kernel(const u16* __restrict__ X, const float* __restrict__ G,
                    const float* __restrict__ Bt, u16* __restrict__ O) {
  const int row = blockIdx.x;
  const int tid = threadIdx.x;
  const u16* xr = X + (size_t)row * 1024;
  ushort4 xv = *(const ushort4*)(xr + tid * 4);
  float v0 = b2f(xv.x), v1 = b2f(xv.y), v2 = b2f(xv.z), v3 = b2f(xv.w);
  float s = v0 + v1 + v2 + v3;
  float q = v0 * v0 + v1 * v1 + v2 * v2 + v3 * v3;
  #pragma unroll
  for (int off = 32; off > 0; off >>= 1) {
    s += __shfl_down(s, off);
    q += __shfl_down(q, off);
  }
  __shared__ float red[8];
  int wave = tid >> 6, lane = tid & 63;
  if (lane == 0) { red[wave] = s; red[4 + wave] = q; }
  __syncthreads();
  s = red[0] + red[1] + red[2] + red[3];
  q = red[4] + red[5] + red[6] + red[7];
  float mean = s * (1.f / 1024.f);
  float var = q * (1.f / 1024.f) - mean * mean;
  float rstd = rsqrtf(var + 1e-3f);
  float4 gv = *(const float4*)(G + tid * 4);
  float4 bv = *(const float4*)(Bt + tid * 4);
  ushort4 ov;
  ov.x = f2b((v0 - mean) * rstd * gv.x + bv.x);
  ov.y = f2b((v1 - mean) * rstd * gv.y + bv.y);
  ov.z = f2b((v2 - mean) * rstd * gv.z + bv.z);
  ov.w = f2b((v3 - mean) * rstd * gv.w + bv.w);
  *(ushort4*)(O + (size_t)row * 1024 + tid * 4) = ov;
}

// ---------------- shared GEMM epilogue (LDS transpose + fused ops) -----------
// EPI 0: qkv 3-part bias; 1: bias+residual (bf16 out); 2: bias+GELU(fast);
// 3: bias+residual (fp32 out).
template <int EPI>
__device__ __forceinline__ void gemm_epilogue(
    u16* smem, f32x4 (&acc)[4][4], void* Cout,
    const float* bias0, const float* bias1, const float* bias2,
    const u16* resid, int N, int m0, int n0,
    int tid, int wm, int wn, int quad, int l16) {
  #pragma unroll
  for (int half = 0; half < 2; ++half) {
    if (wm == half) {
      #pragma unroll
      for (int i = 0; i < 4; ++i) {
        const int fsw = (i * 4 + quad) & 7;     // (lrow>>2)&7
        #pragma unroll
        for (int j = 0; j < 4; ++j) {
          const int chunk = (wn * 8 + j * 2 + (l16 >> 3)) ^ fsw;
          const int base = chunk * 8 + (l16 & 7);
          #pragma unroll
          for (int rr = 0; rr < 4; ++rr) {
            const int lrow = i * 16 + quad * 4 + rr;
            smem[lrow * 128 + base] = f2b(acc[i][j][rr]);
          }
        }
      }
    }
    __syncthreads();
    #pragma unroll
    for (int s = 0; s < 4; ++s) {
      const int lrow = s * 16 + (tid >> 4);
      const int chunk = tid & 15;
      const int fsw = (lrow >> 2) & 7;
      bf16x8 cv = *(const bf16x8*)&smem[lrow * 128 + ((chunk ^ fsw) * 8)];
      const int gr = m0 + half * 64 + lrow;
      const int gc = n0 + chunk * 8;
      const float* bp_ = bias0;
      int cb = gc;
      if (EPI == 0) {
        const int selb = gc >> 10;
        bp_ = (selb == 0) ? bias0 : ((selb == 1) ? bias1 : bias2);
        cb = gc & 1023;
      }
      float4 bv0 = *(const float4*)(bp_ + cb);
      float4 bv1 = *(const float4*)(bp_ + cb + 4);
      float vv[8];
      #pragma unroll
      for (int e = 0; e < 8; ++e) {
        float be = (e < 4) ? ((const float*)&bv0)[e] : ((const float*)&bv1)[e - 4];
        vv[e] = b2f(((const u16*)&cv)[e]) + be;
      }
      if (EPI == 2) {
        #pragma unroll
        for (int e = 0; e < 8; ++e) vv[e] = gelu_fast(vv[e]);
      }
      if (EPI == 1 || EPI == 3) {
        bf16x8 rv = *(const bf16x8*)(resid + (size_t)gr * N + gc);
        #pragma unroll
        for (int e = 0; e < 8; ++e) vv[e] += b2f(((const u16*)&rv)[e]);
      }
      if (EPI == 3) {
        float4 o0 = {vv[0], vv[1], vv[2], vv[3]};
        float4 o1 = {vv[4], vv[5], vv[6], vv[7]};
        float* op = (float*)Cout + (size_t)gr * N + gc;
        *(float4*)op = o0;
        *(float4*)(op + 4) = o1;
      } else {
        bf16x8 ov;
        #pragma unroll
        for (int e = 0; e < 8; ++e) ((u16*)&ov)[e] = f2b(vv[e]);
        *(bf16x8*)((u16*)Cout + (size_t)gr * N + gc) = ov;
      }
    }
    __syncthreads();   // half-0 reads done before half-1 overwrites
  }
}

// ---------------- GEMM variant 2: 64 KiB full double-buffer (R7 proven) -----
// For 512-block launches (proj, FF2): grid caps residency at 2/CU.
template <int EPI>
__global__ __launch_bounds__(256)
void gemm_nt2(const u16* __restrict__ A, const u16* __restrict__ BT,
              void* __restrict__ Cout,
              const float* __restrict__ bias0, const float* __restrict__ bias1,
              const float* __restrict__ bias2, const u16* __restrict__ resid,
              int M, int N, int K, int RA, int RB, int NRn) {
  __shared__ __align__(16) u16 smem[32768];     // 64 KiB: A0,A1,B0,B1
  const int tid = threadIdx.x;

  const int xcd = blockIdx.x & 7;
  const int s_ = blockIdx.x >> 3;
  const int rm = xcd / NRn, rn = xcd - rm * NRn;
  const int lm = s_ / RB, ln = s_ - lm * RB;
  const int m0 = (rm * RA + lm) * 128;
  const int n0 = (rn * RB + ln) * 128;

  const int wave = tid >> 6, lane = tid & 63;
  const int wm = wave & 1, wn = wave >> 1;
  const int quad = lane >> 4, l16 = lane & 15;

  f32x4 acc[4][4];
  #pragma unroll
  for (int i = 0; i < 4; ++i)
    #pragma unroll
    for (int j = 0; j < 4; ++j) acc[i][j] = (f32x4){0.f, 0.f, 0.f, 0.f};

  const int rowS = tid >> 3;
  const int swz = ((tid & 7) ^ ((tid >> 3) & 7)) * 8;
  const u16* aB = A + (size_t)(m0 + rowS) * K + swz;
  const u16* bB = BT + (size_t)(n0 + rowS) * K + swz;
  const size_t rstep = (size_t)32 * K;

  const int nt = K >> 6;

  auto stage = [&](int p, int kt) {
    u16* aD = &smem[(u32)p * 8192 + (u32)tid * 8];
    u16* bD = &smem[16384u + (u32)p * 8192 + (u32)tid * 8];
    const int k0 = kt * 64;
    #pragma unroll
    for (int cc = 0; cc < 4; ++cc) {
      g2l16(aB + k0 + cc * rstep, aD + cc * 2048);
      g2l16(bB + k0 + cc * rstep, bD + cc * 2048);
    }
  };

  stage(0, 0);

  for (int t = 0; t < nt; ++t) {
    const int p = t & 1;
    asm volatile("s_waitcnt vmcnt(0)" ::: "memory");
    __builtin_amdgcn_s_barrier();
    const u16* As = &smem[(u32)p * 8192];
    const u16* Bs = &smem[16384u + (u32)p * 8192];

    bf16x8 aF[2][4], bF[2][4];
    #pragma unroll
    for (int ks = 0; ks < 2; ++ks) {
      const int sOff = (((ks * 4 + quad) ^ (l16 & 7)) * 8);
      #pragma unroll
      for (int i = 0; i < 4; ++i)
        aF[ks][i] = *(const bf16x8*)&As[(wm * 64 + i * 16 + l16) * 64 + sOff];
      #pragma unroll
      for (int j = 0; j < 4; ++j)
        bF[ks][j] = *(const bf16x8*)&Bs[(wn * 64 + j * 16 + l16) * 64 + sOff];
    }
    if (t + 1 < nt) stage(p ^ 1, t + 1);   // prefetch flies under the MFMAs
    #pragma unroll
    for (int ks = 0; ks < 2; ++ks)
      #pragma unroll
      for (int i = 0; i < 4; ++i)
        #pragma unroll
        for (int j = 0; j < 4; ++j)
          acc[i][j] = __builtin_amdgcn_mfma_f32_16x16x32_bf16(
              aF[ks][i], bF[ks][j], acc[i][j], 0, 0, 0);
  }
  __syncthreads();
  gemm_epilogue<EPI>(smem, acc, Cout, bias0, bias1, bias2, resid, N, m0, n0,
                     tid, wm, wn, quad, l16);
}

// ---------------- GEMM variant 3: 48 KiB, 3 blocks/CU (R8/R10-verified) -----
// For >=1536-block launches (QKV, FF1).
template <int EPI>
__global__ __launch_bounds__(256, 3)
void gemm_nt3(const u16* __restrict__ A, const u16* __restrict__ BT,
              void* __restrict__ Cout,
              const float* __restrict__ bias0, const float* __restrict__ bias1,
              const float* __restrict__ bias2, const u16* __restrict__ resid,
              int M, int N, int K, int RA, int RB, int NRn) {
  __shared__ __align__(16) u16 smem[24576];     // 48 KiB: A0,A1,B
  const int tid = threadIdx.x;

  const int xcd = blockIdx.x & 7;
  const int s_ = blockIdx.x >> 3;
  const int rm = xcd / NRn, rn = xcd - rm * NRn;
  const int lm = s_ / RB, ln = s_ - lm * RB;
  const int m0 = (rm * RA + lm) * 128;
  const int n0 = (rn * RB + ln) * 128;

  const int wave = tid >> 6, lane = tid & 63;
  const int wm = wave & 1, wn = wave >> 1;
  const int quad = lane >> 4, l16 = lane & 15;

  f32x4 acc[4][4];
  #pragma unroll
  for (int i = 0; i < 4; ++i)
    #pragma unroll
    for (int j = 0; j < 4; ++j) acc[i][j] = (f32x4){0.f, 0.f, 0.f, 0.f};

  const int rowS = tid >> 3;
  const int swz = ((tid & 7) ^ ((tid >> 3) & 7)) * 8;
  const u16* aB = A + (size_t)(m0 + rowS) * K + swz;
  const u16* bB = BT + (size_t)(n0 + rowS) * K + swz;
  const size_t rstep = (size_t)32 * K;

  const int nt = K >> 6;

  auto stageA = [&](int p, int kt) {
    u16* aD = &smem[(u32)p * 8192 + (u32)tid * 8];
    const int k0 = kt * 64;
    #pragma unroll
    for (int cc = 0; cc < 4; ++cc)
      g2l16(aB + k0 + cc * rstep, aD + cc * 2048);
  };
  auto stageB = [&](int kt) {
    u16* bD = &smem[16384u + (u32)tid * 8];
    const int k0 = kt * 64;
    #pragma unroll
    for (int cc = 0; cc < 4; ++cc)
      g2l16(bB + k0 + cc * rstep, bD + cc * 2048);
  };

  stageA(0, 0); stageB(0);   // prologue

  for (int t = 0; t < nt; ++t) {
    const int p = t & 1;
    asm volatile("s_waitcnt vmcnt(0)" ::: "memory");
    __builtin_amdgcn_s_barrier();
    const u16* As = &smem[(u32)p * 8192];
    const u16* Bs = &smem[16384u];

    bf16x8 aF[2][4], bF[2][4];
    #pragma unroll
    for (int ks = 0; ks < 2; ++ks) {
      const int sOff = (((ks * 4 + quad) ^ (l16 & 7)) * 8);
      #pragma unroll
      for (int j = 0; j < 4; ++j)
        bF[ks][j] = *(const bf16x8*)&Bs[(wn * 64 + j * 16 + l16) * 64 + sOff];
      #pragma unroll
      for (int i = 0; i < 4; ++i)
        aF[ks][i] = *(const bf16x8*)&As[(wm * 64 + i * 16 + l16) * 64 + sOff];
    }
    asm volatile("s_waitcnt lgkmcnt(0)" ::: "memory");
    __builtin_amdgcn_s_barrier();
    if (t + 1 < nt) { stageA(p ^ 1, t + 1); stageB(t + 1); }  // fly under MFMAs
    #pragma unroll
    for (int ks = 0; ks < 2; ++ks)
      #pragma unroll
      for (int i = 0; i < 4; ++i)
        #pragma unroll
        for (int j = 0; j < 4; ++j)
          acc[i][j] = __builtin_amdgcn_mfma_f32_16x16x32_bf16(
              aF[ks][i], bF[ks][j], acc[i][j], 0, 0, 0);
  }
  __syncthreads();
  gemm_epilogue<EPI>(smem, acc, Cout, bias0, bias1, bias2, resid, N, m0, n0,
                     tid, wm, wn, quad, l16);
}

// ---------------- attention (no softmax!): M = scale * K^T V per (b,h) -------
// d2 split into 4 quarters (grid.y = 4) -> 512 blocks = 2/CU (R7 win, kept).
// Round-11: output M^T as SPLIT-BF16 pair (hi = f2b(m), lo = f2b(m - hi)):
// downstream MFMA computes Q@M1 + Q@M2 => effective ~fp21 precision for M,
// strictly below Q's own bf16 rounding -> numerics identical to fp32-M path.
// Writes coalesced (lanes = consecutive d1).
__global__ __launch_bounds__(256)
void attn_m_kernel(const u16* __restrict__ qkv, u16* __restrict__ MT1,
                   u16* __restrict__ MT2) {
  const int bh = blockIdx.x;
  const int qtr = blockIdx.y;                   // d2 cols [qtr*16, qtr*16+16)
  const int b = bh >> 4, h = bh & 15;
  const u16* Kp = qkv + (size_t)b * 1024 * 3072 + 1024 + h * 64;
  const u16* Vp = Kp + 1024 + qtr * 16;
  __shared__ __align__(16) float Ks[64 * 64];
  __shared__ __align__(16) float Vs[64 * 20];   // stride 20: 16B-aligned rows
  const int tid = threadIdx.x;
  const int d1 = tid & 63, d2q = (tid >> 6) * 4;
  const int lr = tid >> 3, lc = (tid & 7) * 8;  // K staging: 32 rows x 8 cols
  const int vr = tid >> 2, vc = (tid & 3) * 4;  // V staging: 64 rows x 4 cols
  float acc[4];
  #pragma unroll
  for (int j = 0; j < 4; ++j) acc[j] = 0.f;
  for (int t0 = 0; t0 < 1024; t0 += 64) {
    __syncthreads();
    #pragma unroll
    for (int it = 0; it < 2; ++it) {
      int r = it * 32 + lr;
      const u16* ks = Kp + (size_t)(t0 + r) * 3072 + lc;
      ushort4 a0 = *(const ushort4*)ks;
      ushort4 a1 = *(const ushort4*)(ks + 4);
      float* kd = &Ks[r * 64 + lc];
      kd[0] = b2f(a0.x); kd[1] = b2f(a0.y); kd[2] = b2f(a0.z); kd[3] = b2f(a0.w);
      kd[4] = b2f(a1.x); kd[5] = b2f(a1.y); kd[6] = b2f(a1.z); kd[7] = b2f(a1.w);
    }
    {
      const u16* vs = Vp + (size_t)(t0 + vr) * 3072 + vc;
      ushort4 c0 = *(const ushort4*)vs;
      float4 vvw = {b2f(c0.x), b2f(c0.y), b2f(c0.z), b2f(c0.w)};
      *(float4*)&Vs[vr * 20 + vc] = vvw;
    }
    __syncthreads();
    #pragma unroll 8
    for (int tt = 0; tt < 64; ++tt) {
      float kv = Ks[tt * 64 + d1];
      float4 vv = *(const float4*)&Vs[tt * 20 + d2q];
      #pragma unroll
      for (int j = 0; j < 4; ++j) acc[j] += kv * ((const float*)&vv)[j];
    }
  }
  #pragma unroll
  for (int j = 0; j < 4; ++j) {
    float m = acc[j] * 0.03125f;                 // C^-0.5 = 1/32
    u16 hi = f2b(m);
    u16 lo = f2b(m - b2f(hi));
    const size_t off = (size_t)bh * 4096 + (qtr * 16 + d2q + j) * 64 + d1;
    MT1[off] = hi;
    MT2[off] = lo;
  }
}

// ---------------- heads = Q @ (M1+M2) via MFMA, concat layout out ------------
// Round-11: replaces the VALU attn_h (was LDS-issue-bound, ~45 us inferred).
// Per (bh, t-quarter): NT-GEMM with A = Q[256][64] (k=d1 contiguous),
// BT = M^T[64][64] split-bf16 pair. Single K-iteration (K=64): stage via the
// gemm's pre-swizzled global_load_lds pattern, plain __syncthreads (compiler
// inserts the waitcnts), 64 MFMA/wave, padded-stride LDS epilogue ->
// coalesced 16B stores into cat[b*1024+t][h*64+d2].
__global__ __launch_bounds__(256)
void attn_h_mfma(const u16* __restrict__ qkv, const u16* __restrict__ MT1,
                 const u16* __restrict__ MT2, u16* __restrict__ cat) {
  const int bh = blockIdx.x;                    // 128
  const int tq = blockIdx.y;                    // 4 quarters of 256 t-rows
  const int b = bh >> 4, h = bh & 15;
  __shared__ __align__(16) u16 smem[24576];     // 48 KiB
  u16* Qs = smem;                               // [256][64]  16384 u16
  u16* Ms1 = smem + 16384;                      // [64][64]    4096 u16
  u16* Ms2 = smem + 20480;                      // [64][64]    4096 u16
  const int tid = threadIdx.x;
  const int wv = tid >> 6, lane = tid & 63;
  const int quad = lane >> 4, l16 = lane & 15;

  // staging: pre-swizzled global source, linear LDS dest (gemm pattern).
  const int rowS = tid >> 3;                    // 0..31
  const int swz = ((tid & 7) ^ (rowS & 7)) * 8;
  {
    const u16* Qg = qkv + (size_t)(b * 1024 + tq * 256 + rowS) * 3072 +
                    h * 64 + swz;
    u16* qD = &Qs[(u32)tid * 8];
    #pragma unroll
    for (int cc = 0; cc < 8; ++cc)
      g2l16(Qg + (size_t)cc * 32 * 3072, qD + cc * 2048);
    const size_t moff = (size_t)bh * 4096 + rowS * 64 + swz;
    g2l16(MT1 + moff, &Ms1[(u32)tid * 8]);
    g2l16(MT1 + moff + 2048, &Ms1[(u32)tid * 8 + 2048]);
    g2l16(MT2 + moff, &Ms2[(u32)tid * 8]);
    g2l16(MT2 + moff + 2048, &Ms2[(u32)tid * 8 + 2048]);
  }
  asm volatile("s_waitcnt vmcnt(0)" ::: "memory");
  __syncthreads();

  f32x4 acc[4][4];
  #pragma unroll
  for (int i = 0; i < 4; ++i)
    #pragma unroll
    for (int j = 0; j < 4; ++j) acc[i][j] = (f32x4){0.f, 0.f, 0.f, 0.f};

  bf16x8 aF[2][4], b1F[2][4], b2F[2][4];
  #pragma unroll
  for (int ks = 0; ks < 2; ++ks) {
    const int sOff = (((ks * 4 + quad) ^ (l16 & 7)) * 8);
    #pragma unroll
    for (int i = 0; i < 4; ++i)
      aF[ks][i] = *(const bf16x8*)&Qs[(wv * 64 + i * 16 + l16) * 64 + sOff];
    #pragma unroll
    for (int j = 0; j < 4; ++j) {
      b1F[ks][j] = *(const bf16x8*)&Ms1[(j * 16 + l16) * 64 + sOff];
      b2F[ks][j] = *(const bf16x8*)&Ms2[(j * 16 + l16) * 64 + sOff];
    }
  }
  #pragma unroll
  for (int ks = 0; ks < 2; ++ks)
    #pragma unroll
    for (int i = 0; i < 4; ++i)
      #pragma unroll
      for (int j = 0; j < 4; ++j) {
        acc[i][j] = __builtin_amdgcn_mfma_f32_16x16x32_bf16(
            aF[ks][i], b1F[ks][j], acc[i][j], 0, 0, 0);
        acc[i][j] = __builtin_amdgcn_mfma_f32_16x16x32_bf16(
            aF[ks][i], b2F[ks][j], acc[i][j], 0, 0, 0);
      }
  __syncthreads();   // all waves' LDS frag reads complete before overwrite

  // epilogue: per-wave [64][72] u16 region (stride 72 breaks pow2 banks),
  // C/D layout col=l16, row=quad*4+rr (m89), then coalesced 16B stores.
  {
    u16* eS = smem + wv * 4608;                 // 64*72 u16 = 9216 B
    #pragma unroll
    for (int i = 0; i < 4; ++i)
      #pragma unroll
      for (int j = 0; j < 4; ++j)
        #pragma unroll
        for (int rr = 0; rr < 4; ++rr)
          eS[(i * 16 + quad * 4 + rr) * 72 + j * 16 + l16] =
              f2b(acc[i][j][rr]);
  }
  __syncthreads();
  const int bT = b * 1024 + tq * 256;
  #pragma unroll
  for (int s = 0; s < 8; ++s) {
    const int g = s * 32 + (tid >> 3);          // 0..255
    bf16x8 v = *(const bf16x8*)&smem[(g >> 6) * 4608 + (g & 63) * 72 +
                                     (tid & 7) * 8];
    *(bf16x8*)(cat + (size_t)(bT + g) * 1024 + h * 64 + (tid & 7) * 8) = v;
  }
}

extern "C" void kernel_launch(void* const* d_in, const int* in_sizes, int n_in,
                              void* d_out, int out_size, void* d_ws, size_t ws_size,
                              hipStream_t stream) {
  (void)in_sizes; (void)n_in; (void)out_size; (void)ws_size;
  const float* x     = (const float*)d_in[0];
  const float* Wq    = (const float*)d_in[1];
  const float* bq    = (const float*)d_in[2];
  const float* Wk    = (const float*)d_in[3];
  const float* bk    = (const float*)d_in[4];
  const float* Wv    = (const float*)d_in[5];
  const float* bv    = (const float*)d_in[6];
  const float* Wp    = (const float*)d_in[7];
  const float* bp    = (const float*)d_in[8];
  const float* W1    = (const float*)d_in[9];
  const float* b1    = (const float*)d_in[10];
  const float* W2    = (const float*)d_in[11];
  const float* b2    = (const float*)d_in[12];
  const float* ln1w  = (const float*)d_in[13];
  const float* ln1b  = (const float*)d_in[14];
  const float* ln2w  = (const float*)d_in[15];
  const float* ln2b  = (const float*)d_in[16];

  char* ws = (char*)d_ws;
  u16* x1    = (u16*)(ws);                        // 16 MiB  [8192,1024] bf16
  u16* qkv   = (u16*)(ws + 16777216);             // 48 MiB  [8192,3072] bf16
  u16* cat   = (u16*)(ws + 67108864);             // 16 MiB  [8192,1024] bf16
  u16* yb    = (u16*)(ws + 83886080);             // 16 MiB  [8192,1024] bf16
  u16* x2    = (u16*)(ws + 100663296);            // 16 MiB  [8192,1024] bf16
  u16* WqkvT = (u16*)(ws + 117440512);            // 6 MiB   [3072,1024] bf16
  u16* WpT   = (u16*)(ws + 123731968);            // 2 MiB   [1024,1024] bf16
  u16* W1T   = (u16*)(ws + 125829120);            // 8 MiB   [4096,1024] bf16
  u16* W2T   = (u16*)(ws + 134217728);            // 8 MiB   [1024,4096] bf16
  u16* MT1   = (u16*)(ws + 142606336);            // 1 MiB   [128,64,64] bf16 hi
  u16* MT2   = (u16*)(ws + 143654912);            // 1 MiB   [128,64,64] bf16 lo
  u16* hb    = (u16*)(ws + 16777216);             // 64 MiB, reuses dead qkv+cat

  repack_qkv_tiled<<<dim3(16, 48), 256, 0, stream>>>(Wq, Wk, Wv, WqkvT);
  transpose_tiled<<<dim3(32, 32), 256, 0, stream>>>(Wp, WpT, 1024, 1024);
  transpose_tiled<<<dim3(128, 32), 256, 0, stream>>>(W1, W1T, 4096, 1024);
  transpose_tiled<<<dim3(32, 128), 256, 0, stream>>>(W2, W2T, 1024, 4096);

  ln_f32_kernel<<<8192, 256, 0, stream>>>(x, ln1w, ln1b, x1);

  // QKV : 1536 blocks (6/CU grid) -> 3-buffer variant; regions 16x12, 4x2
  gemm_nt3<0><<<1536, 256, 0, stream>>>(x1, WqkvT, qkv, bq, bk, bv, nullptr,
                                        8192, 3072, 1024, 16, 12, 2);
  attn_m_kernel<<<dim3(128, 4), 256, 0, stream>>>(qkv, MT1, MT2);
  attn_h_mfma<<<dim3(128, 4), 256, 0, stream>>>(qkv, MT1, MT2, cat);

  // proj : 512 blocks (2/CU grid cap) -> 64 KiB dbuf variant; regions 8x8, 8x1
  gemm_nt2<1><<<512, 256, 0, stream>>>(cat, WpT, yb, bp, nullptr, nullptr, x1,
                                       8192, 1024, 1024, 8, 8, 1);
  ln_bf16_kernel<<<8192, 256, 0, stream>>>(yb, ln2w, ln2b, x2);

  // FF1 : 2048 blocks (8/CU grid) -> 3-buffer variant; regions 16x16, 4x2
  gemm_nt3<2><<<2048, 256, 0, stream>>>(x2, W1T, hb, b1, nullptr, nullptr, nullptr,
                                        8192, 4096, 1024, 16, 16, 2);
  // FF2 : 512 blocks (2/CU grid cap) -> 64 KiB dbuf variant; regions 8x8, 8x1
  gemm_nt2<3><<<512, 256, 0, stream>>>(hb, W2T, d_out, b2, nullptr, nullptr, x2,
                                       8192, 1024, 4096, 8, 8, 1);
}